// Round 3
// baseline (641.181 us; speedup 1.0000x reference)
//
#include <hip/hip_runtime.h>
#include <stdint.h>

#define M_TOT 32768   // B*N = 8*4096
#define D_DIM 1024
#define NCOLS 3072    // 3*D

typedef __bf16 bf16x8 __attribute__((ext_vector_type(8)));
typedef float  f32x4  __attribute__((ext_vector_type(4)));

typedef const __attribute__((address_space(1))) void gvoid_t;
typedef __attribute__((address_space(3))) void lvoid_t;

__device__ __forceinline__ void gload_lds16(const void* g, void* l) {
  __builtin_amdgcn_global_load_lds((gvoid_t*)g, (lvoid_t*)l, 16, 0, 0);
}

__device__ __forceinline__ uint16_t f2bf(float f) {
  uint32_t u = __float_as_uint(f);
  u += 0x7fffu + ((u >> 16) & 1u);   // RNE (inputs are finite randoms)
  return (uint16_t)(u >> 16);
}
__device__ __forceinline__ float bf2f(uint32_t u16) {
  union { uint32_t u; float f; } c; c.u = u16 << 16; return c.f;
}

// ---------------------------------------------------------------- casts ----
__global__ void __launch_bounds__(256) cast_x_k(const float* __restrict__ x,
                                                uint16_t* __restrict__ xb) {
  const int64_t i = ((int64_t)blockIdx.x * 256 + threadIdx.x) * 4;
  float4 v = *(const float4*)(x + i);
  ushort4 o;
  o.x = f2bf(v.x); o.y = f2bf(v.y); o.z = f2bf(v.z); o.w = f2bf(v.w);
  *(ushort4*)(xb + i) = o;
}

__global__ void __launch_bounds__(256) cast_w_k(const float* __restrict__ Wq,
                                                const float* __restrict__ Wk,
                                                const float* __restrict__ Wv,
                                                uint16_t* __restrict__ wcat) {
  const int64_t i = ((int64_t)blockIdx.x * 256 + threadIdx.x) * 4;  // < 3*2^20
  const int wsel = (int)(i >> 20);
  const int64_t l = i & 1048575;
  const float* src = (wsel == 0) ? Wq : (wsel == 1) ? Wk : Wv;
  float4 v = *(const float4*)(src + l);
  ushort4 o;
  o.x = f2bf(v.x); o.y = f2bf(v.y); o.z = f2bf(v.z); o.w = f2bf(v.w);
  *(ushort4*)(wcat + i) = o;
}

// ----------------------------------------------------------------- GEMM ----
// C[m, e] = sum_d xb[m,d] * wcat[e,d]   (A row-major, B^T row-major)
// 128x128 tile, BK=64, 256 threads = 4 waves (2x2 of 64x64), 16x16x32 bf16 MFMA.
// Q columns (e<1024) -> fp32 into d_out; K,V -> bf16 into ws.
__global__ void __launch_bounds__(256) gemm_qkv(
    const uint16_t* __restrict__ xb, const uint16_t* __restrict__ wcat,
    float* __restrict__ outQ, uint16_t* __restrict__ Kb,
    uint16_t* __restrict__ Vb) {
  __shared__ uint16_t As[128 * 64];
  __shared__ uint16_t Bs[128 * 64];
  const int tid  = threadIdx.x;
  const int lane = tid & 63;
  const int wid  = tid >> 6;
  const int wr   = wid >> 1;   // wave row 0..1
  const int wcn  = wid & 1;    // wave col 0..1
  const int row0 = blockIdx.y * 128;
  const int e0   = blockIdx.x * 128;

  // staging: per wave-instruction, 64 lanes x 16B = 8 rows of 64 bf16
  const int sr = lane >> 3;          // row within 8-row stripe
  const int sc = (lane & 7) * 8;     // col (elems)
  const uint16_t* gA = xb   + (int64_t)(row0 + wid * 32 + sr) * D_DIM + sc;
  const uint16_t* gB = wcat + (int64_t)(e0   + wid * 32 + sr) * D_DIM + sc;

  f32x4 acc[4][4] = {};
  const int lr = lane & 15;
  const int kg = lane >> 4;

  for (int kt = 0; kt < D_DIM; kt += 64) {
#pragma unroll
    for (int i = 0; i < 4; ++i) {
      gload_lds16(gA + (int64_t)i * 8 * D_DIM + kt, &As[(wid * 32 + i * 8) * 64]);
      gload_lds16(gB + (int64_t)i * 8 * D_DIM + kt, &Bs[(wid * 32 + i * 8) * 64]);
    }
    __syncthreads();   // drains vmcnt before any wave reads LDS
#pragma unroll
    for (int kk = 0; kk < 2; ++kk) {
      bf16x8 af[4], bb[4];
#pragma unroll
      for (int m = 0; m < 4; ++m)
        af[m] = *(const bf16x8*)&As[(wr * 64 + m * 16 + lr) * 64 + kk * 32 + kg * 8];
#pragma unroll
      for (int n = 0; n < 4; ++n)
        bb[n] = *(const bf16x8*)&Bs[(wcn * 64 + n * 16 + lr) * 64 + kk * 32 + kg * 8];
#pragma unroll
      for (int m = 0; m < 4; ++m)
#pragma unroll
        for (int n = 0; n < 4; ++n)
          acc[m][n] = __builtin_amdgcn_mfma_f32_16x16x32_bf16(af[m], bb[n],
                                                              acc[m][n], 0, 0, 0);
    }
    __syncthreads();   // LDS reuse next K-step
  }

  // epilogue: C/D layout col=lane&15, row=(lane>>4)*4+r (verified m89/m91)
  const int proj = e0 >> 10;  // 0=Q,1=K,2=V
  const int lr4 = kg * 4;
  if (proj == 0) {
    float* o = outQ + (int64_t)row0 * D_DIM + e0;
#pragma unroll
    for (int m = 0; m < 4; ++m)
#pragma unroll
      for (int r = 0; r < 4; ++r) {
        const int rr = wr * 64 + m * 16 + lr4 + r;
#pragma unroll
        for (int n = 0; n < 4; ++n)
          o[(int64_t)rr * D_DIM + wcn * 64 + n * 16 + lr] = acc[m][n][r];
      }
  } else {
    uint16_t* o = (proj == 1 ? Kb : Vb) + (int64_t)row0 * D_DIM + (e0 - proj * D_DIM);
#pragma unroll
    for (int m = 0; m < 4; ++m)
#pragma unroll
      for (int r = 0; r < 4; ++r) {
        const int rr = wr * 64 + m * 16 + lr4 + r;
#pragma unroll
        for (int n = 0; n < 4; ++n)
          o[(int64_t)rr * D_DIM + wcn * 64 + n * 16 + lr] = f2bf(acc[m][n][r]);
      }
  }
}

// ---------------------------------------------- gf = sum_n K_hat .* V -----
// grid 512 (8 batches x 64 groups), 64 rows each. Per row: block-reduce ||K||^2,
// acc += K*V/||K||. Writes per-block partial rows.
__global__ void __launch_bounds__(256) kv_partial(
    const uint16_t* __restrict__ Kb, const uint16_t* __restrict__ Vb,
    float* __restrict__ partial) {
  const int blk = blockIdx.x;
  const int b = blk >> 6, g = blk & 63;
  const int t = threadIdx.x;
  const int c0 = t * 4;
  __shared__ float red[4];
  float a0 = 0.f, a1 = 0.f, a2 = 0.f, a3 = 0.f;
  for (int r = 0; r < 64; ++r) {
    const int64_t row = ((int64_t)b * 4096 + g * 64 + r) * D_DIM;
    const uint2 ku = *(const uint2*)(Kb + row + c0);
    const uint2 vu = *(const uint2*)(Vb + row + c0);
    const float k0 = bf2f(ku.x & 0xffffu), k1 = bf2f(ku.x >> 16);
    const float k2 = bf2f(ku.y & 0xffffu), k3 = bf2f(ku.y >> 16);
    const float v0 = bf2f(vu.x & 0xffffu), v1 = bf2f(vu.x >> 16);
    const float v2 = bf2f(vu.y & 0xffffu), v3 = bf2f(vu.y >> 16);
    float ss = k0 * k0 + k1 * k1 + k2 * k2 + k3 * k3;
#pragma unroll
    for (int off = 32; off > 0; off >>= 1) ss += __shfl_xor(ss, off);
    if ((t & 63) == 0) red[t >> 6] = ss;
    __syncthreads();
    const float tot = red[0] + red[1] + red[2] + red[3];
    __syncthreads();
    const float rn = 1.0f / fmaxf(sqrtf(tot), 1e-12f);
    a0 += k0 * v0 * rn; a1 += k1 * v1 * rn;
    a2 += k2 * v2 * rn; a3 += k3 * v3 * rn;
  }
  float* p = partial + (int64_t)blk * D_DIM + c0;
  p[0] = a0; p[1] = a1; p[2] = a2; p[3] = a3;
}

__global__ void __launch_bounds__(256) kv_reduce(const float* __restrict__ partial,
                                                 float* __restrict__ gf) {
  const int i = blockIdx.x * 256 + threadIdx.x;  // 0..8191
  const int b = i >> 10, e = i & 1023;
  float s = 0.f;
  for (int g = 0; g < 64; ++g)
    s += partial[((int64_t)(b * 64 + g)) * D_DIM + e];
  gf[i] = s;
}

// -------------------------------- out = (Q/||Q||) * gf[b]   (in place) ----
__global__ void __launch_bounds__(256) finalize_out(float* __restrict__ out,
                                                    const float* __restrict__ gf) {
  const int bid = blockIdx.x;          // 0..2047, 16 rows each
  const int t = threadIdx.x;
  const int64_t r0 = (int64_t)bid * 16;
  const int b = (int)(r0 >> 12);       // 4096 rows per batch
  const int c0 = t * 4;
  const float4 g4 = *(const float4*)(gf + (int64_t)b * D_DIM + c0);
  __shared__ float red[4];
  for (int r = 0; r < 16; ++r) {
    float* rowp = out + (r0 + r) * D_DIM + c0;
    float4 q = *(const float4*)rowp;
    float ss = q.x * q.x + q.y * q.y + q.z * q.z + q.w * q.w;
#pragma unroll
    for (int off = 32; off > 0; off >>= 1) ss += __shfl_xor(ss, off);
    if ((t & 63) == 0) red[t >> 6] = ss;
    __syncthreads();
    const float tot = red[0] + red[1] + red[2] + red[3];
    __syncthreads();
    const float rn = 1.0f / fmaxf(sqrtf(tot), 1e-12f);
    q.x = q.x * rn * g4.x; q.y = q.y * rn * g4.y;
    q.z = q.z * rn * g4.z; q.w = q.w * rn * g4.w;
    *(float4*)rowp = q;
  }
}

// -------------------------------------------------------------- launch ----
extern "C" void kernel_launch(void* const* d_in, const int* in_sizes, int n_in,
                              void* d_out, int out_size, void* d_ws, size_t ws_size,
                              hipStream_t stream) {
  const float* x  = (const float*)d_in[0];
  const float* Wq = (const float*)d_in[1];
  const float* Wk = (const float*)d_in[2];
  const float* Wv = (const float*)d_in[3];
  float* out = (float*)d_out;

  uint8_t* w = (uint8_t*)d_ws;
  // ws layout (bytes): xb 64MiB | wcat 6MiB | Kb 64MiB | Vb 64MiB | partial 2MiB | gf 32KiB
  uint16_t* xb   = (uint16_t*)(w);
  uint16_t* wcat = (uint16_t*)(w + (size_t)67108864);
  uint16_t* Kb   = (uint16_t*)(w + (size_t)73400320);
  uint16_t* Vb   = (uint16_t*)(w + (size_t)140509184);
  float* partial = (float*)(w + (size_t)207618048);
  float* gf      = (float*)(w + (size_t)209715200);

  cast_x_k   <<<32768, 256, 0, stream>>>(x, xb);
  cast_w_k   <<<3072, 256, 0, stream>>>(Wq, Wk, Wv, wcat);
  gemm_qkv   <<<dim3(24, 256), 256, 0, stream>>>(xb, wcat, out, Kb, Vb);
  kv_partial <<<512, 256, 0, stream>>>(Kb, Vb, partial);
  kv_reduce  <<<32, 256, 0, stream>>>(partial, gf);
  finalize_out<<<2048, 256, 0, stream>>>(out, gf);
}

// Round 4
// 601.414 us; speedup vs baseline: 1.0661x; 1.0661x over previous
//
#include <hip/hip_runtime.h>
#include <stdint.h>

#define M_TOT 32768   // B*N = 8*4096
#define D_DIM 1024
#define NCOLS 3072    // 3*D

typedef __bf16 bf16x8 __attribute__((ext_vector_type(8)));
typedef float  f32x4  __attribute__((ext_vector_type(4)));

typedef const __attribute__((address_space(1))) void gvoid_t;
typedef __attribute__((address_space(3))) void lvoid_t;

__device__ __forceinline__ void gload_lds16(const void* g, void* l) {
  __builtin_amdgcn_global_load_lds((gvoid_t*)g, (lvoid_t*)l, 16, 0, 0);
}

__device__ __forceinline__ uint16_t f2bf(float f) {
  uint32_t u = __float_as_uint(f);
  u += 0x7fffu + ((u >> 16) & 1u);   // RNE (inputs are finite randoms)
  return (uint16_t)(u >> 16);
}
__device__ __forceinline__ float bf2f(uint32_t u16) {
  union { uint32_t u; float f; } c; c.u = u16 << 16; return c.f;
}

// ---------------------------------------------------------------- casts ----
__global__ void __launch_bounds__(256) cast_x_k(const float* __restrict__ x,
                                                uint16_t* __restrict__ xb) {
  const int64_t i = ((int64_t)blockIdx.x * 256 + threadIdx.x) * 4;
  float4 v = *(const float4*)(x + i);
  ushort4 o;
  o.x = f2bf(v.x); o.y = f2bf(v.y); o.z = f2bf(v.z); o.w = f2bf(v.w);
  *(ushort4*)(xb + i) = o;
}

__global__ void __launch_bounds__(256) cast_w_k(const float* __restrict__ Wq,
                                                const float* __restrict__ Wk,
                                                const float* __restrict__ Wv,
                                                uint16_t* __restrict__ wcat) {
  const int64_t i = ((int64_t)blockIdx.x * 256 + threadIdx.x) * 4;  // < 3*2^20
  const int wsel = (int)(i >> 20);
  const int64_t l = i & 1048575;
  const float* src = (wsel == 0) ? Wq : (wsel == 1) ? Wk : Wv;
  float4 v = *(const float4*)(src + l);
  ushort4 o;
  o.x = f2bf(v.x); o.y = f2bf(v.y); o.z = f2bf(v.z); o.w = f2bf(v.w);
  *(ushort4*)(wcat + i) = o;
}

// ----------------------------------------------------------------- GEMM ----
// C[m, e] = sum_d xb[m,d] * wcat[e,d]   (A row-major, B^T row-major)
// 128x128 tile, BK=64, 256 threads = 4 waves (2x2 of 64x64), 16x16x32 bf16 MFMA.
// Q columns (e<1024) -> fp32 into d_out; K,V -> bf16 into ws.
// (Known-good anchor from round 3; untouched this round.)
__global__ void __launch_bounds__(256) gemm_qkv(
    const uint16_t* __restrict__ xb, const uint16_t* __restrict__ wcat,
    float* __restrict__ outQ, uint16_t* __restrict__ Kb,
    uint16_t* __restrict__ Vb) {
  __shared__ uint16_t As[128 * 64];
  __shared__ uint16_t Bs[128 * 64];
  const int tid  = threadIdx.x;
  const int lane = tid & 63;
  const int wid  = tid >> 6;
  const int wr   = wid >> 1;   // wave row 0..1
  const int wcn  = wid & 1;    // wave col 0..1
  const int row0 = blockIdx.y * 128;
  const int e0   = blockIdx.x * 128;

  const int sr = lane >> 3;          // row within 8-row stripe
  const int sc = (lane & 7) * 8;     // col (elems)
  const uint16_t* gA = xb   + (int64_t)(row0 + wid * 32 + sr) * D_DIM + sc;
  const uint16_t* gB = wcat + (int64_t)(e0   + wid * 32 + sr) * D_DIM + sc;

  f32x4 acc[4][4] = {};
  const int lr = lane & 15;
  const int kg = lane >> 4;

  for (int kt = 0; kt < D_DIM; kt += 64) {
#pragma unroll
    for (int i = 0; i < 4; ++i) {
      gload_lds16(gA + (int64_t)i * 8 * D_DIM + kt, &As[(wid * 32 + i * 8) * 64]);
      gload_lds16(gB + (int64_t)i * 8 * D_DIM + kt, &Bs[(wid * 32 + i * 8) * 64]);
    }
    __syncthreads();   // drains vmcnt before any wave reads LDS
#pragma unroll
    for (int kk = 0; kk < 2; ++kk) {
      bf16x8 af[4], bb[4];
#pragma unroll
      for (int m = 0; m < 4; ++m)
        af[m] = *(const bf16x8*)&As[(wr * 64 + m * 16 + lr) * 64 + kk * 32 + kg * 8];
#pragma unroll
      for (int n = 0; n < 4; ++n)
        bb[n] = *(const bf16x8*)&Bs[(wcn * 64 + n * 16 + lr) * 64 + kk * 32 + kg * 8];
#pragma unroll
      for (int m = 0; m < 4; ++m)
#pragma unroll
        for (int n = 0; n < 4; ++n)
          acc[m][n] = __builtin_amdgcn_mfma_f32_16x16x32_bf16(af[m], bb[n],
                                                              acc[m][n], 0, 0, 0);
    }
    __syncthreads();   // LDS reuse next K-step
  }

  // epilogue: C/D layout col=lane&15, row=(lane>>4)*4+r (verified m89/m91)
  const int proj = e0 >> 10;  // 0=Q,1=K,2=V
  const int lr4 = kg * 4;
  if (proj == 0) {
    float* o = outQ + (int64_t)row0 * D_DIM + e0;
#pragma unroll
    for (int m = 0; m < 4; ++m)
#pragma unroll
      for (int r = 0; r < 4; ++r) {
        const int rr = wr * 64 + m * 16 + lr4 + r;
#pragma unroll
        for (int n = 0; n < 4; ++n)
          o[(int64_t)rr * D_DIM + wcn * 64 + n * 16 + lr] = acc[m][n][r];
      }
  } else {
    uint16_t* o = (proj == 1 ? Kb : Vb) + (int64_t)row0 * D_DIM + (e0 - proj * D_DIM);
#pragma unroll
    for (int m = 0; m < 4; ++m)
#pragma unroll
      for (int r = 0; r < 4; ++r) {
        const int rr = wr * 64 + m * 16 + lr4 + r;
#pragma unroll
        for (int n = 0; n < 4; ++n)
          o[(int64_t)rr * D_DIM + wcn * 64 + n * 16 + lr] = f2bf(acc[m][n][r]);
      }
  }
}

// ---------------------------------------------- gf = sum_n K_hat .* V -----
// Wave-per-row, shuffle-only row reduction (no barriers in hot loop).
// 1024 blocks = 8 batches x 128 groups; block covers 32 rows (4 waves x 8).
// Lane owns 16 cols as 2 passes of 8 (lane-contiguous uint4 loads).
// One LDS combine at block end -> partial[1024][1024].
__global__ void __launch_bounds__(256) kv_partial(
    const uint16_t* __restrict__ Kb, const uint16_t* __restrict__ Vb,
    float* __restrict__ partial) {
  const int blk = blockIdx.x;              // 0..1023
  const int b = blk >> 7, g = blk & 127;   // 32 rows per block
  const int t = threadIdx.x;
  const int w = t >> 6, lane = t & 63;
  __shared__ float sacc[4][1024];
  float acc[16];
#pragma unroll
  for (int j = 0; j < 16; ++j) acc[j] = 0.f;
  const int64_t rbase = ((int64_t)b * 4096 + g * 32 + w * 8) * D_DIM;
#pragma unroll 2
  for (int r = 0; r < 8; ++r) {
    const int64_t row = rbase + (int64_t)r * D_DIM;
    float k[16], v[16];
#pragma unroll
    for (int p = 0; p < 2; ++p) {
      const int off = (p * 64 + lane) * 8;   // 8 bf16 per lane, lane-contiguous
      const uint4 ku = *(const uint4*)(Kb + row + off);
      const uint4 vu = *(const uint4*)(Vb + row + off);
      const uint32_t kw[4] = {ku.x, ku.y, ku.z, ku.w};
      const uint32_t vw[4] = {vu.x, vu.y, vu.z, vu.w};
#pragma unroll
      for (int q = 0; q < 4; ++q) {
        k[p * 8 + q * 2]     = bf2f(kw[q] & 0xffffu);
        k[p * 8 + q * 2 + 1] = bf2f(kw[q] >> 16);
        v[p * 8 + q * 2]     = bf2f(vw[q] & 0xffffu);
        v[p * 8 + q * 2 + 1] = bf2f(vw[q] >> 16);
      }
    }
    float ss = 0.f;
#pragma unroll
    for (int j = 0; j < 16; ++j) ss += k[j] * k[j];
#pragma unroll
    for (int o = 32; o > 0; o >>= 1) ss += __shfl_xor(ss, o);
    const float rn = 1.0f / fmaxf(sqrtf(ss), 1e-12f);
#pragma unroll
    for (int j = 0; j < 16; ++j) acc[j] += k[j] * v[j] * rn;
  }
  // combine the 4 waves once (col of acc[p*8+j] is p*512 + lane*8 + j)
#pragma unroll
  for (int p = 0; p < 2; ++p)
#pragma unroll
    for (int j = 0; j < 8; ++j)
      sacc[w][p * 512 + lane * 8 + j] = acc[p * 8 + j];
  __syncthreads();
  float* prow = partial + (int64_t)blk * 1024;
#pragma unroll
  for (int c = t; c < 1024; c += 256)
    prow[c] = sacc[0][c] + sacc[1][c] + sacc[2][c] + sacc[3][c];
}

__global__ void __launch_bounds__(256) kv_reduce(const float* __restrict__ partial,
                                                 float* __restrict__ gf) {
  const int i = blockIdx.x * 256 + threadIdx.x;  // 0..8191
  const int b = i >> 10, e = i & 1023;
  float s = 0.f;
  for (int g = 0; g < 128; ++g)
    s += partial[((int64_t)(b * 128 + g) << 10) + e];
  gf[i] = s;
}

// -------------------------------- out = (Q/||Q||) * gf[b]   (in place) ----
// Wave-per-row, shuffle-only, no barriers. 8192 blocks x 4 waves.
__global__ void __launch_bounds__(256) finalize_out(float* __restrict__ out,
                                                    const float* __restrict__ gf) {
  const int64_t row = (int64_t)blockIdx.x * 4 + (threadIdx.x >> 6);
  const int lane = threadIdx.x & 63;
  const int b = (int)(row >> 12);            // 4096 rows per batch
  float* rp = out + row * D_DIM;
  const float* gp = gf + (int64_t)b * D_DIM;
  float4 q[4];
#pragma unroll
  for (int p = 0; p < 4; ++p) q[p] = *(const float4*)(rp + (p * 64 + lane) * 4);
  float ss = 0.f;
#pragma unroll
  for (int p = 0; p < 4; ++p)
    ss += q[p].x * q[p].x + q[p].y * q[p].y + q[p].z * q[p].z + q[p].w * q[p].w;
#pragma unroll
  for (int o = 32; o > 0; o >>= 1) ss += __shfl_xor(ss, o);
  const float rn = 1.0f / fmaxf(sqrtf(ss), 1e-12f);
#pragma unroll
  for (int p = 0; p < 4; ++p) {
    const float4 g4 = *(const float4*)(gp + (p * 64 + lane) * 4);
    q[p].x *= rn * g4.x; q[p].y *= rn * g4.y;
    q[p].z *= rn * g4.z; q[p].w *= rn * g4.w;
    *(float4*)(rp + (p * 64 + lane) * 4) = q[p];
  }
}

// -------------------------------------------------------------- launch ----
extern "C" void kernel_launch(void* const* d_in, const int* in_sizes, int n_in,
                              void* d_out, int out_size, void* d_ws, size_t ws_size,
                              hipStream_t stream) {
  const float* x  = (const float*)d_in[0];
  const float* Wq = (const float*)d_in[1];
  const float* Wk = (const float*)d_in[2];
  const float* Wv = (const float*)d_in[3];
  float* out = (float*)d_out;

  uint8_t* w = (uint8_t*)d_ws;
  // ws layout (bytes): xb 64MiB | wcat 6MiB | Kb 64MiB | Vb 64MiB
  // partial (4MiB) + gf alias the xb region: xb is dead after gemm_qkv,
  // and stream ordering guarantees gemm completes before kv_partial.
  uint16_t* xb   = (uint16_t*)(w);
  uint16_t* wcat = (uint16_t*)(w + (size_t)67108864);
  uint16_t* Kb   = (uint16_t*)(w + (size_t)73400320);
  uint16_t* Vb   = (uint16_t*)(w + (size_t)140509184);
  float* partial = (float*)(w);                         // 1024*1024*4 = 4MiB
  float* gf      = (float*)(w + (size_t)4194304);       // 8*1024*4 = 32KiB

  cast_x_k   <<<32768, 256, 0, stream>>>(x, xb);
  cast_w_k   <<<3072, 256, 0, stream>>>(Wq, Wk, Wv, wcat);
  gemm_qkv   <<<dim3(24, 256), 256, 0, stream>>>(xb, wcat, out, Kb, Vb);
  kv_partial <<<1024, 256, 0, stream>>>(Kb, Vb, partial);
  kv_reduce  <<<32, 256, 0, stream>>>(partial, gf);
  finalize_out<<<8192, 256, 0, stream>>>(out, gf);
}

// Round 8
// 525.731 us; speedup vs baseline: 1.2196x; 1.1440x over previous
//
#include <hip/hip_runtime.h>
#include <stdint.h>

#define D_DIM 1024

typedef __bf16 bf16x8 __attribute__((ext_vector_type(8)));
typedef float  f32x4  __attribute__((ext_vector_type(4)));

typedef const __attribute__((address_space(1))) void gvoid_t;
typedef __attribute__((address_space(3))) void lvoid_t;

__device__ __forceinline__ void gload_lds16(const void* g, void* l) {
  __builtin_amdgcn_global_load_lds((gvoid_t*)g, (lvoid_t*)l, 16, 0, 0);
}

__device__ __forceinline__ uint16_t f2bf(float f) {
  uint32_t u = __float_as_uint(f);
  u += 0x7fffu + ((u >> 16) & 1u);   // RNE
  return (uint16_t)(u >> 16);
}
__device__ __forceinline__ float bf2f(uint32_t u16) {
  union { uint32_t u; float f; } c; c.u = u16 << 16; return c.f;
}

// ---------------------------------------------------------------- casts ----
__global__ void __launch_bounds__(256) cast_x_k(const float* __restrict__ x,
                                                uint16_t* __restrict__ xb) {
  const int64_t i = ((int64_t)blockIdx.x * 256 + threadIdx.x) * 4;
  float4 v = *(const float4*)(x + i);
  ushort4 o;
  o.x = f2bf(v.x); o.y = f2bf(v.y); o.z = f2bf(v.z); o.w = f2bf(v.w);
  *(ushort4*)(xb + i) = o;
}

__global__ void __launch_bounds__(256) cast_w_k(const float* __restrict__ Wq,
                                                const float* __restrict__ Wk,
                                                const float* __restrict__ Wv,
                                                uint16_t* __restrict__ wcat) {
  const int64_t i = ((int64_t)blockIdx.x * 256 + threadIdx.x) * 4;
  const int wsel = (int)(i >> 20);
  const int64_t l = i & 1048575;
  const float* src = (wsel == 0) ? Wq : (wsel == 1) ? Wk : Wv;
  float4 v = *(const float4*)(src + l);
  ushort4 o;
  o.x = f2bf(v.x); o.y = f2bf(v.y); o.z = f2bf(v.z); o.w = f2bf(v.w);
  *(ushort4*)(wcat + i) = o;
}

// ----------------------------------------------------------------- GEMM ----
// 256x256 tile, BK=64, 512 thr = 8 waves (2M x 4N), 8-phase schedule with
// counted vmcnt (T3+T4), st_16x32 LDS swizzle (T2), setprio (T5).
// LDS: sA/sB double-buffered [2][256][64] bf16 = 128 KiB.
// Swizzle (elem): e ^= ((e>>8)&1)<<4 — staged via pre-swizzled global source
// (chunk c ^= ((c>>5)&1)<<1), read via same XOR (rule #21: both sides).
// Stage schedule per iter i (compute t0=2i buf0 ph0-3, t1=2i+1 buf1 ph4-7):
//   ph0: A(t1)h0  ph1: A(t1)h1  ph2: B(t2)h0  ph3: B(t2)h1 | vmcnt(4)
//   ph4: A(t2)h0  ph5: A(t2)h1  ph6: B(t3)h0  ph7: B(t3)h1 | vmcnt(4)
// Every overwrite is >=1 barrier after its last reader; vmcnt(4) leaves only
// the newest 2 half-tiles (4 loads) outstanding, which are never needed yet.
__global__ void __launch_bounds__(512, 2) gemm_qkv8(
    const uint16_t* __restrict__ xb, const uint16_t* __restrict__ wcat,
    float* __restrict__ outQ, uint16_t* __restrict__ Kb,
    uint16_t* __restrict__ Vb) {
  alignas(16) __shared__ uint16_t sA[2][16384];
  alignas(16) __shared__ uint16_t sB[2][16384];
  const int tid = threadIdx.x, lane = tid & 63, wid = tid >> 6;
  const int wm = wid >> 2, wn = wid & 3;

  // XCD-aware bijective swizzle (1536 % 8 == 0)
  const int bid = blockIdx.x;
  const int wg = (bid & 7) * 192 + (bid >> 3);
  const int tm = wg / 12, tn = wg % 12;
  const int row0 = tm * 256, e0 = tn * 256;

  // staging precompute: chunk c (16B) -> pre-swizzled source chunk
  const int c0 = tid;
  const int c1 = tid + 512;
  const int cs0 = c0 ^ (((c0 >> 5) & 1) << 1);
  const int cs1 = c1 ^ (((c1 >> 5) & 1) << 1);
  const int sr0 = cs0 >> 3, sk0 = (cs0 & 7) * 8;
  const int sr1 = cs1 >> 3, sk1 = (cs1 & 7) * 8;
  const uint16_t* gA = xb + (int64_t)row0 * D_DIM;
  const uint16_t* gB = wcat + (int64_t)e0 * D_DIM;
  const int ldsw = wid * 512;   // this wave's j=0 chunk-set elem offset in half

  // fragment-read precompute (swizzled)
  const int lr = lane & 15, kg = lane >> 4;
  const int flip = (lr & 4) ? 16 : 0;
  const int kq0 = (kg * 8) ^ flip;
  const int kq1 = (32 + kg * 8) ^ flip;
  const int arow = (wm * 128 + lr) * 64;
  const int brow = (wn * 64 + lr) * 64;

  f32x4 acc[8][4] = {};
  bf16x8 bfr[4][2];

#define STAGE_A(d, h, kt) do {                                               \
    gload_lds16(gA + (int64_t)((h)*128 + sr0) * D_DIM + (kt) + sk0,          \
                &sA[d][(h)*8192 + ldsw]);                                    \
    gload_lds16(gA + (int64_t)((h)*128 + sr1) * D_DIM + (kt) + sk1,          \
                &sA[d][(h)*8192 + 4096 + ldsw]);                             \
  } while (0)
#define STAGE_B(d, h, kt) do {                                               \
    gload_lds16(gB + (int64_t)((h)*128 + sr0) * D_DIM + (kt) + sk0,          \
                &sB[d][(h)*8192 + ldsw]);                                    \
    gload_lds16(gB + (int64_t)((h)*128 + sr1) * D_DIM + (kt) + sk1,          \
                &sB[d][(h)*8192 + 4096 + ldsw]);                             \
  } while (0)

#define MFMA __builtin_amdgcn_mfma_f32_16x16x32_bf16
#define PHASE(qq, dd, STAGE_STMT, VM_STMT) do {                              \
    if ((qq) == 0) {                                                         \
      bfr[0][0] = *(const bf16x8*)&sB[dd][brow + 0 * 1024 + kq0];            \
      bfr[0][1] = *(const bf16x8*)&sB[dd][brow + 0 * 1024 + kq1];            \
      bfr[1][0] = *(const bf16x8*)&sB[dd][brow + 1 * 1024 + kq0];            \
      bfr[1][1] = *(const bf16x8*)&sB[dd][brow + 1 * 1024 + kq1];            \
      bfr[2][0] = *(const bf16x8*)&sB[dd][brow + 2 * 1024 + kq0];            \
      bfr[2][1] = *(const bf16x8*)&sB[dd][brow + 2 * 1024 + kq1];            \
      bfr[3][0] = *(const bf16x8*)&sB[dd][brow + 3 * 1024 + kq0];            \
      bfr[3][1] = *(const bf16x8*)&sB[dd][brow + 3 * 1024 + kq1];            \
    }                                                                        \
    bf16x8 a00 = *(const bf16x8*)&sA[dd][arow + (2*(qq)) * 1024 + kq0];      \
    bf16x8 a01 = *(const bf16x8*)&sA[dd][arow + (2*(qq)) * 1024 + kq1];      \
    bf16x8 a10 = *(const bf16x8*)&sA[dd][arow + (2*(qq)+1) * 1024 + kq0];    \
    bf16x8 a11 = *(const bf16x8*)&sA[dd][arow + (2*(qq)+1) * 1024 + kq1];    \
    STAGE_STMT;                                                              \
    asm volatile("" ::: "memory");                                           \
    __builtin_amdgcn_s_barrier();                                            \
    __builtin_amdgcn_s_setprio(1);                                           \
    acc[2*(qq)][0]   = MFMA(a00, bfr[0][0], acc[2*(qq)][0],   0,0,0);        \
    acc[2*(qq)+1][0] = MFMA(a10, bfr[0][0], acc[2*(qq)+1][0], 0,0,0);        \
    acc[2*(qq)][0]   = MFMA(a01, bfr[0][1], acc[2*(qq)][0],   0,0,0);        \
    acc[2*(qq)+1][0] = MFMA(a11, bfr[0][1], acc[2*(qq)+1][0], 0,0,0);        \
    acc[2*(qq)][1]   = MFMA(a00, bfr[1][0], acc[2*(qq)][1],   0,0,0);        \
    acc[2*(qq)+1][1] = MFMA(a10, bfr[1][0], acc[2*(qq)+1][1], 0,0,0);        \
    acc[2*(qq)][1]   = MFMA(a01, bfr[1][1], acc[2*(qq)][1],   0,0,0);        \
    acc[2*(qq)+1][1] = MFMA(a11, bfr[1][1], acc[2*(qq)+1][1], 0,0,0);        \
    acc[2*(qq)][2]   = MFMA(a00, bfr[2][0], acc[2*(qq)][2],   0,0,0);        \
    acc[2*(qq)+1][2] = MFMA(a10, bfr[2][0], acc[2*(qq)+1][2], 0,0,0);        \
    acc[2*(qq)][2]   = MFMA(a01, bfr[2][1], acc[2*(qq)][2],   0,0,0);        \
    acc[2*(qq)+1][2] = MFMA(a11, bfr[2][1], acc[2*(qq)+1][2], 0,0,0);        \
    acc[2*(qq)][3]   = MFMA(a00, bfr[3][0], acc[2*(qq)][3],   0,0,0);        \
    acc[2*(qq)+1][3] = MFMA(a10, bfr[3][0], acc[2*(qq)+1][3], 0,0,0);        \
    acc[2*(qq)][3]   = MFMA(a01, bfr[3][1], acc[2*(qq)][3],   0,0,0);        \
    acc[2*(qq)+1][3] = MFMA(a11, bfr[3][1], acc[2*(qq)+1][3], 0,0,0);        \
    __builtin_amdgcn_s_setprio(0);                                           \
    VM_STMT;                                                                 \
    asm volatile("" ::: "memory");                                           \
    __builtin_amdgcn_s_barrier();                                            \
  } while (0)

  // prologue: B(0), A(0) -> buf0; B(1) -> buf1. Last 4 loads = B(1).
  STAGE_B(0, 0, 0);  STAGE_B(0, 1, 0);
  STAGE_A(0, 0, 0);  STAGE_A(0, 1, 0);
  STAGE_B(1, 0, 64); STAGE_B(1, 1, 64);
  asm volatile("s_waitcnt vmcnt(4)" ::: "memory");
  __builtin_amdgcn_s_barrier();

  int ktb = 0;
  for (int i = 0; i < 8; ++i) {
    const bool nl = (i < 7);
    const int kt1 = ktb + 64, kt2 = ktb + 128, kt3 = ktb + 192;
    // tile t0 = 2i from buf0
    PHASE(0, 0, STAGE_A(1, 0, kt1), ((void)0));
    PHASE(1, 0, STAGE_A(1, 1, kt1), ((void)0));
    PHASE(2, 0, if (nl) STAGE_B(0, 0, kt2), ((void)0));
    PHASE(3, 0, if (nl) STAGE_B(0, 1, kt2),
          { if (nl) asm volatile("s_waitcnt vmcnt(4)" ::: "memory");
            else    asm volatile("s_waitcnt vmcnt(0)" ::: "memory"); });
    // tile t1 = 2i+1 from buf1
    PHASE(0, 1, if (nl) STAGE_A(0, 0, kt2), ((void)0));
    PHASE(1, 1, if (nl) STAGE_A(0, 1, kt2), ((void)0));
    PHASE(2, 1, if (nl) STAGE_B(1, 0, kt3), ((void)0));
    PHASE(3, 1, if (nl) STAGE_B(1, 1, kt3),
          { if (nl) asm volatile("s_waitcnt vmcnt(4)" ::: "memory"); });
    ktb += 128;
  }

  // epilogue: C/D layout col=lane&15, row=kg*4+rr (verified m89/m91)
  const int proj = e0 >> 10;  // 0=Q,1=K,2=V
  if (proj == 0) {
    float* o = outQ + (int64_t)(row0 + wm * 128) * D_DIM + e0 + wn * 64;
#pragma unroll
    for (int m = 0; m < 8; ++m)
#pragma unroll
      for (int rr = 0; rr < 4; ++rr) {
        const int64_t rofs = (int64_t)(m * 16 + kg * 4 + rr) * D_DIM;
#pragma unroll
        for (int n = 0; n < 4; ++n)
          o[rofs + n * 16 + lr] = acc[m][n][rr];
      }
  } else {
    uint16_t* o = (proj == 1 ? Kb : Vb) +
                  (int64_t)(row0 + wm * 128) * D_DIM + (e0 - proj * 1024) + wn * 64;
#pragma unroll
    for (int m = 0; m < 8; ++m)
#pragma unroll
      for (int rr = 0; rr < 4; ++rr) {
        const int64_t rofs = (int64_t)(m * 16 + kg * 4 + rr) * D_DIM;
#pragma unroll
        for (int n = 0; n < 4; ++n)
          o[rofs + n * 16 + lr] = f2bf(acc[m][n][rr]);
      }
  }
#undef PHASE
#undef MFMA
#undef STAGE_A
#undef STAGE_B
}

// ---------------------------------------------- gf = sum_n K_hat .* V -----
__global__ void __launch_bounds__(256) kv_partial(
    const uint16_t* __restrict__ Kb, const uint16_t* __restrict__ Vb,
    float* __restrict__ partial) {
  const int blk = blockIdx.x;              // 0..1023
  const int b = blk >> 7, g = blk & 127;   // 32 rows per block
  const int t = threadIdx.x;
  const int w = t >> 6, lane = t & 63;
  __shared__ float sacc[4][1024];
  float acc[16];
#pragma unroll
  for (int j = 0; j < 16; ++j) acc[j] = 0.f;
  const int64_t rbase = ((int64_t)b * 4096 + g * 32 + w * 8) * D_DIM;
#pragma unroll 2
  for (int r = 0; r < 8; ++r) {
    const int64_t row = rbase + (int64_t)r * D_DIM;
    float k[16], v[16];
#pragma unroll
    for (int p = 0; p < 2; ++p) {
      const int off = (p * 64 + lane) * 8;
      const uint4 ku = *(const uint4*)(Kb + row + off);
      const uint4 vu = *(const uint4*)(Vb + row + off);
      const uint32_t kw[4] = {ku.x, ku.y, ku.z, ku.w};
      const uint32_t vw[4] = {vu.x, vu.y, vu.z, vu.w};
#pragma unroll
      for (int q = 0; q < 4; ++q) {
        k[p * 8 + q * 2]     = bf2f(kw[q] & 0xffffu);
        k[p * 8 + q * 2 + 1] = bf2f(kw[q] >> 16);
        v[p * 8 + q * 2]     = bf2f(vw[q] & 0xffffu);
        v[p * 8 + q * 2 + 1] = bf2f(vw[q] >> 16);
      }
    }
    float ss = 0.f;
#pragma unroll
    for (int j = 0; j < 16; ++j) ss += k[j] * k[j];
#pragma unroll
    for (int o = 32; o > 0; o >>= 1) ss += __shfl_xor(ss, o);
    const float rn = 1.0f / fmaxf(sqrtf(ss), 1e-12f);
#pragma unroll
    for (int j = 0; j < 16; ++j) acc[j] += k[j] * v[j] * rn;
  }
#pragma unroll
  for (int p = 0; p < 2; ++p)
#pragma unroll
    for (int j = 0; j < 8; ++j)
      sacc[w][p * 512 + lane * 8 + j] = acc[p * 8 + j];
  __syncthreads();
  float* prow = partial + (int64_t)blk * 1024;
#pragma unroll
  for (int c = t; c < 1024; c += 256)
    prow[c] = sacc[0][c] + sacc[1][c] + sacc[2][c] + sacc[3][c];
}

__global__ void __launch_bounds__(256) kv_reduce(const float* __restrict__ partial,
                                                 float* __restrict__ gf) {
  const int i = blockIdx.x * 256 + threadIdx.x;  // 0..8191
  const int b = i >> 10, e = i & 1023;
  float s = 0.f;
  for (int g = 0; g < 128; ++g)
    s += partial[((int64_t)(b * 128 + g) << 10) + e];
  gf[i] = s;
}

// -------------------------------- out = (Q/||Q||) * gf[b]   (in place) ----
__global__ void __launch_bounds__(256) finalize_out(float* __restrict__ out,
                                                    const float* __restrict__ gf) {
  const int64_t row = (int64_t)blockIdx.x * 4 + (threadIdx.x >> 6);
  const int lane = threadIdx.x & 63;
  const int b = (int)(row >> 12);
  float* rp = out + row * D_DIM;
  const float* gp = gf + (int64_t)b * D_DIM;
  float4 q[4];
#pragma unroll
  for (int p = 0; p < 4; ++p) q[p] = *(const float4*)(rp + (p * 64 + lane) * 4);
  float ss = 0.f;
#pragma unroll
  for (int p = 0; p < 4; ++p)
    ss += q[p].x * q[p].x + q[p].y * q[p].y + q[p].z * q[p].z + q[p].w * q[p].w;
#pragma unroll
  for (int o = 32; o > 0; o >>= 1) ss += __shfl_xor(ss, o);
  const float rn = 1.0f / fmaxf(sqrtf(ss), 1e-12f);
#pragma unroll
  for (int p = 0; p < 4; ++p) {
    const float4 g4 = *(const float4*)(gp + (p * 64 + lane) * 4);
    q[p].x *= rn * g4.x; q[p].y *= rn * g4.y;
    q[p].z *= rn * g4.z; q[p].w *= rn * g4.w;
    *(float4*)(rp + (p * 64 + lane) * 4) = q[p];
  }
}

// -------------------------------------------------------------- launch ----
extern "C" void kernel_launch(void* const* d_in, const int* in_sizes, int n_in,
                              void* d_out, int out_size, void* d_ws, size_t ws_size,
                              hipStream_t stream) {
  const float* x  = (const float*)d_in[0];
  const float* Wq = (const float*)d_in[1];
  const float* Wk = (const float*)d_in[2];
  const float* Wv = (const float*)d_in[3];
  float* out = (float*)d_out;

  uint8_t* w = (uint8_t*)d_ws;
  uint16_t* xb   = (uint16_t*)(w);
  uint16_t* wcat = (uint16_t*)(w + (size_t)67108864);
  uint16_t* Kb   = (uint16_t*)(w + (size_t)73400320);
  uint16_t* Vb   = (uint16_t*)(w + (size_t)140509184);
  float* partial = (float*)(w);                         // aliases xb (dead)
  float* gf      = (float*)(w + (size_t)4194304);

  cast_x_k   <<<32768, 256, 0, stream>>>(x, xb);
  cast_w_k   <<<3072, 256, 0, stream>>>(Wq, Wk, Wv, wcat);
  gemm_qkv8  <<<1536, 512, 0, stream>>>(xb, wcat, out, Kb, Vb);
  kv_partial <<<1024, 256, 0, stream>>>(Kb, Vb, partial);
  kv_reduce  <<<32, 256, 0, stream>>>(partial, gf);
  finalize_out<<<8192, 256, 0, stream>>>(out, gf);
}

// Round 9
// 515.808 us; speedup vs baseline: 1.2431x; 1.0192x over previous
//
#include <hip/hip_runtime.h>
#include <stdint.h>

#define D_DIM 1024

typedef __bf16 bf16x8 __attribute__((ext_vector_type(8)));
typedef float  f32x4  __attribute__((ext_vector_type(4)));

typedef const __attribute__((address_space(1))) void gvoid_t;
typedef __attribute__((address_space(3))) void lvoid_t;

__device__ __forceinline__ void gload_lds16(const void* g, void* l) {
  __builtin_amdgcn_global_load_lds((gvoid_t*)g, (lvoid_t*)l, 16, 0, 0);
}

__device__ __forceinline__ uint16_t f2bf(float f) {
  uint32_t u = __float_as_uint(f);
  u += 0x7fffu + ((u >> 16) & 1u);   // RNE
  return (uint16_t)(u >> 16);
}
__device__ __forceinline__ float bf2f(uint32_t u16) {
  union { uint32_t u; float f; } c; c.u = u16 << 16; return c.f;
}

// ---------------------------------------------------------------- casts ----
__global__ void __launch_bounds__(256) cast_x_k(const float* __restrict__ x,
                                                uint16_t* __restrict__ xb) {
  const int64_t i = ((int64_t)blockIdx.x * 256 + threadIdx.x) * 4;
  float4 v = *(const float4*)(x + i);
  ushort4 o;
  o.x = f2bf(v.x); o.y = f2bf(v.y); o.z = f2bf(v.z); o.w = f2bf(v.w);
  *(ushort4*)(xb + i) = o;
}

__global__ void __launch_bounds__(256) cast_w_k(const float* __restrict__ Wq,
                                                const float* __restrict__ Wk,
                                                const float* __restrict__ Wv,
                                                uint16_t* __restrict__ wcat) {
  const int64_t i = ((int64_t)blockIdx.x * 256 + threadIdx.x) * 4;
  const int wsel = (int)(i >> 20);
  const int64_t l = i & 1048575;
  const float* src = (wsel == 0) ? Wq : (wsel == 1) ? Wk : Wv;
  float4 v = *(const float4*)(src + l);
  ushort4 o;
  o.x = f2bf(v.x); o.y = f2bf(v.y); o.z = f2bf(v.z); o.w = f2bf(v.w);
  *(ushort4*)(wcat + i) = o;
}

// ----------------------------------------------------------------- GEMM ----
// 256x256 tile, BK=64, 512 thr = 8 waves (2M x 4N), 8-phase schedule with
// counted vmcnt (T3+T4), 3-bit LDS slot swizzle (T2, G4 form), setprio (T5).
// LDS: sA/sB double-buffered [2][256][64] bf16 = 128 KiB.
// Swizzle (16B slot within 64-elem row): slot ^= row&7 — stage via
// pre-swizzled global source chunk cs = c ^ ((c>>3)&7); read via
// kq0 = (kg ^ (lr&7))*8 (rule #21: both sides, same involution).
// Row&7 == lr&7 for every fragment read (row offsets are multiples of 16),
// so each 16-lane group spreads over all 8 slots x 2 lanes = conflict-free.
// Stage schedule per iter i (compute t0=2i buf0 ph0-3, t1=2i+1 buf1 ph4-7):
//   ph0: A(t1)h0  ph1: A(t1)h1  ph2: B(t2)h0  ph3: B(t2)h1 | vmcnt(4)
//   ph4: A(t2)h0  ph5: A(t2)h1  ph6: B(t3)h0  ph7: B(t3)h1 | vmcnt(4)
// Every overwrite is >=1 barrier after its last reader; vmcnt(4) leaves only
// the newest 2 half-tiles (4 loads) outstanding, which are never needed yet.
__global__ void __launch_bounds__(512, 2) gemm_qkv8(
    const uint16_t* __restrict__ xb, const uint16_t* __restrict__ wcat,
    float* __restrict__ outQ, uint16_t* __restrict__ Kb,
    uint16_t* __restrict__ Vb) {
  alignas(16) __shared__ uint16_t sA[2][16384];
  alignas(16) __shared__ uint16_t sB[2][16384];
  const int tid = threadIdx.x, lane = tid & 63, wid = tid >> 6;
  const int wm = wid >> 2, wn = wid & 3;

  // XCD-aware bijective swizzle (1536 % 8 == 0)
  const int bid = blockIdx.x;
  const int wg = (bid & 7) * 192 + (bid >> 3);
  const int tm = wg / 12, tn = wg % 12;
  const int row0 = tm * 256, e0 = tn * 256;

  // staging precompute: chunk c (16B) -> pre-swizzled source chunk
  const int c0 = tid;
  const int c1 = tid + 512;
  const int cs0 = c0 ^ ((c0 >> 3) & 7);
  const int cs1 = c1 ^ ((c1 >> 3) & 7);
  const int sr0 = cs0 >> 3, sk0 = (cs0 & 7) * 8;
  const int sr1 = cs1 >> 3, sk1 = (cs1 & 7) * 8;
  const uint16_t* gA = xb + (int64_t)row0 * D_DIM;
  const uint16_t* gB = wcat + (int64_t)e0 * D_DIM;
  const int ldsw = wid * 512;   // this wave's j=0 chunk-set elem offset in half

  // fragment-read precompute (3-bit slot swizzle)
  const int lr = lane & 15, kg = lane >> 4;
  const int kq0 = (kg ^ (lr & 7)) * 8;
  const int kq1 = kq0 ^ 32;
  const int arow = (wm * 128 + lr) * 64;
  const int brow = (wn * 64 + lr) * 64;

  f32x4 acc[8][4] = {};
  bf16x8 bfr[4][2];

#define STAGE_A(d, h, kt) do {                                               \
    gload_lds16(gA + (int64_t)((h)*128 + sr0) * D_DIM + (kt) + sk0,          \
                &sA[d][(h)*8192 + ldsw]);                                    \
    gload_lds16(gA + (int64_t)((h)*128 + sr1) * D_DIM + (kt) + sk1,          \
                &sA[d][(h)*8192 + 4096 + ldsw]);                             \
  } while (0)
#define STAGE_B(d, h, kt) do {                                               \
    gload_lds16(gB + (int64_t)((h)*128 + sr0) * D_DIM + (kt) + sk0,          \
                &sB[d][(h)*8192 + ldsw]);                                    \
    gload_lds16(gB + (int64_t)((h)*128 + sr1) * D_DIM + (kt) + sk1,          \
                &sB[d][(h)*8192 + 4096 + ldsw]);                             \
  } while (0)

#define MFMA __builtin_amdgcn_mfma_f32_16x16x32_bf16
#define PHASE(qq, dd, STAGE_STMT, VM_STMT) do {                              \
    if ((qq) == 0) {                                                         \
      bfr[0][0] = *(const bf16x8*)&sB[dd][brow + 0 * 1024 + kq0];            \
      bfr[0][1] = *(const bf16x8*)&sB[dd][brow + 0 * 1024 + kq1];            \
      bfr[1][0] = *(const bf16x8*)&sB[dd][brow + 1 * 1024 + kq0];            \
      bfr[1][1] = *(const bf16x8*)&sB[dd][brow + 1 * 1024 + kq1];            \
      bfr[2][0] = *(const bf16x8*)&sB[dd][brow + 2 * 1024 + kq0];            \
      bfr[2][1] = *(const bf16x8*)&sB[dd][brow + 2 * 1024 + kq1];            \
      bfr[3][0] = *(const bf16x8*)&sB[dd][brow + 3 * 1024 + kq0];            \
      bfr[3][1] = *(const bf16x8*)&sB[dd][brow + 3 * 1024 + kq1];            \
    }                                                                        \
    bf16x8 a00 = *(const bf16x8*)&sA[dd][arow + (2*(qq)) * 1024 + kq0];      \
    bf16x8 a01 = *(const bf16x8*)&sA[dd][arow + (2*(qq)) * 1024 + kq1];      \
    bf16x8 a10 = *(const bf16x8*)&sA[dd][arow + (2*(qq)+1) * 1024 + kq0];    \
    bf16x8 a11 = *(const bf16x8*)&sA[dd][arow + (2*(qq)+1) * 1024 + kq1];    \
    STAGE_STMT;                                                              \
    asm volatile("" ::: "memory");                                           \
    __builtin_amdgcn_s_barrier();                                            \
    __builtin_amdgcn_s_setprio(1);                                           \
    acc[2*(qq)][0]   = MFMA(a00, bfr[0][0], acc[2*(qq)][0],   0,0,0);        \
    acc[2*(qq)+1][0] = MFMA(a10, bfr[0][0], acc[2*(qq)+1][0], 0,0,0);        \
    acc[2*(qq)][0]   = MFMA(a01, bfr[0][1], acc[2*(qq)][0],   0,0,0);        \
    acc[2*(qq)+1][0] = MFMA(a11, bfr[0][1], acc[2*(qq)+1][0], 0,0,0);        \
    acc[2*(qq)][1]   = MFMA(a00, bfr[1][0], acc[2*(qq)][1],   0,0,0);        \
    acc[2*(qq)+1][1] = MFMA(a10, bfr[1][0], acc[2*(qq)+1][1], 0,0,0);        \
    acc[2*(qq)][1]   = MFMA(a01, bfr[1][1], acc[2*(qq)][1],   0,0,0);        \
    acc[2*(qq)+1][1] = MFMA(a11, bfr[1][1], acc[2*(qq)+1][1], 0,0,0);        \
    acc[2*(qq)][2]   = MFMA(a00, bfr[2][0], acc[2*(qq)][2],   0,0,0);        \
    acc[2*(qq)+1][2] = MFMA(a10, bfr[2][0], acc[2*(qq)+1][2], 0,0,0);        \
    acc[2*(qq)][2]   = MFMA(a01, bfr[2][1], acc[2*(qq)][2],   0,0,0);        \
    acc[2*(qq)+1][2] = MFMA(a11, bfr[2][1], acc[2*(qq)+1][2], 0,0,0);        \
    acc[2*(qq)][3]   = MFMA(a00, bfr[3][0], acc[2*(qq)][3],   0,0,0);        \
    acc[2*(qq)+1][3] = MFMA(a10, bfr[3][0], acc[2*(qq)+1][3], 0,0,0);        \
    acc[2*(qq)][3]   = MFMA(a01, bfr[3][1], acc[2*(qq)][3],   0,0,0);        \
    acc[2*(qq)+1][3] = MFMA(a11, bfr[3][1], acc[2*(qq)+1][3], 0,0,0);        \
    __builtin_amdgcn_s_setprio(0);                                           \
    VM_STMT;                                                                 \
    asm volatile("" ::: "memory");                                           \
    __builtin_amdgcn_s_barrier();                                            \
  } while (0)

  // prologue: B(0), A(0) -> buf0; B(1) -> buf1. Last 4 loads = B(1).
  STAGE_B(0, 0, 0);  STAGE_B(0, 1, 0);
  STAGE_A(0, 0, 0);  STAGE_A(0, 1, 0);
  STAGE_B(1, 0, 64); STAGE_B(1, 1, 64);
  asm volatile("s_waitcnt vmcnt(4)" ::: "memory");
  __builtin_amdgcn_s_barrier();

  int ktb = 0;
  for (int i = 0; i < 8; ++i) {
    const bool nl = (i < 7);
    const int kt1 = ktb + 64, kt2 = ktb + 128, kt3 = ktb + 192;
    // tile t0 = 2i from buf0
    PHASE(0, 0, STAGE_A(1, 0, kt1), ((void)0));
    PHASE(1, 0, STAGE_A(1, 1, kt1), ((void)0));
    PHASE(2, 0, if (nl) STAGE_B(0, 0, kt2), ((void)0));
    PHASE(3, 0, if (nl) STAGE_B(0, 1, kt2),
          { if (nl) asm volatile("s_waitcnt vmcnt(4)" ::: "memory");
            else    asm volatile("s_waitcnt vmcnt(0)" ::: "memory"); });
    // tile t1 = 2i+1 from buf1
    PHASE(0, 1, if (nl) STAGE_A(0, 0, kt2), ((void)0));
    PHASE(1, 1, if (nl) STAGE_A(0, 1, kt2), ((void)0));
    PHASE(2, 1, if (nl) STAGE_B(1, 0, kt3), ((void)0));
    PHASE(3, 1, if (nl) STAGE_B(1, 1, kt3),
          { if (nl) asm volatile("s_waitcnt vmcnt(4)" ::: "memory"); });
    ktb += 128;
  }

  // epilogue: C/D layout col=lane&15, row=kg*4+rr (verified m89/m91)
  const int proj = e0 >> 10;  // 0=Q,1=K,2=V
  if (proj == 0) {
    float* o = outQ + (int64_t)(row0 + wm * 128) * D_DIM + e0 + wn * 64;
#pragma unroll
    for (int m = 0; m < 8; ++m)
#pragma unroll
      for (int rr = 0; rr < 4; ++rr) {
        const int64_t rofs = (int64_t)(m * 16 + kg * 4 + rr) * D_DIM;
#pragma unroll
        for (int n = 0; n < 4; ++n)
          o[rofs + n * 16 + lr] = acc[m][n][rr];
      }
  } else {
    uint16_t* o = (proj == 1 ? Kb : Vb) +
                  (int64_t)(row0 + wm * 128) * D_DIM + (e0 - proj * 1024) + wn * 64;
#pragma unroll
    for (int m = 0; m < 8; ++m)
#pragma unroll
      for (int rr = 0; rr < 4; ++rr) {
        const int64_t rofs = (int64_t)(m * 16 + kg * 4 + rr) * D_DIM;
#pragma unroll
        for (int n = 0; n < 4; ++n)
          o[rofs + n * 16 + lr] = f2bf(acc[m][n][rr]);
      }
  }
#undef PHASE
#undef MFMA
#undef STAGE_A
#undef STAGE_B
}

// ---------------------------------------------- gf = sum_n K_hat .* V -----
__global__ void __launch_bounds__(256) kv_partial(
    const uint16_t* __restrict__ Kb, const uint16_t* __restrict__ Vb,
    float* __restrict__ partial) {
  const int blk = blockIdx.x;              // 0..1023
  const int b = blk >> 7, g = blk & 127;   // 32 rows per block
  const int t = threadIdx.x;
  const int w = t >> 6, lane = t & 63;
  __shared__ float sacc[4][1024];
  float acc[16];
#pragma unroll
  for (int j = 0; j < 16; ++j) acc[j] = 0.f;
  const int64_t rbase = ((int64_t)b * 4096 + g * 32 + w * 8) * D_DIM;
#pragma unroll 2
  for (int r = 0; r < 8; ++r) {
    const int64_t row = rbase + (int64_t)r * D_DIM;
    float k[16], v[16];
#pragma unroll
    for (int p = 0; p < 2; ++p) {
      const int off = (p * 64 + lane) * 8;
      const uint4 ku = *(const uint4*)(Kb + row + off);
      const uint4 vu = *(const uint4*)(Vb + row + off);
      const uint32_t kw[4] = {ku.x, ku.y, ku.z, ku.w};
      const uint32_t vw[4] = {vu.x, vu.y, vu.z, vu.w};
#pragma unroll
      for (int q = 0; q < 4; ++q) {
        k[p * 8 + q * 2]     = bf2f(kw[q] & 0xffffu);
        k[p * 8 + q * 2 + 1] = bf2f(kw[q] >> 16);
        v[p * 8 + q * 2]     = bf2f(vw[q] & 0xffffu);
        v[p * 8 + q * 2 + 1] = bf2f(vw[q] >> 16);
      }
    }
    float ss = 0.f;
#pragma unroll
    for (int j = 0; j < 16; ++j) ss += k[j] * k[j];
#pragma unroll
    for (int o = 32; o > 0; o >>= 1) ss += __shfl_xor(ss, o);
    const float rn = 1.0f / fmaxf(sqrtf(ss), 1e-12f);
#pragma unroll
    for (int j = 0; j < 16; ++j) acc[j] += k[j] * v[j] * rn;
  }
#pragma unroll
  for (int p = 0; p < 2; ++p)
#pragma unroll
    for (int j = 0; j < 8; ++j)
      sacc[w][p * 512 + lane * 8 + j] = acc[p * 8 + j];
  __syncthreads();
  float* prow = partial + (int64_t)blk * 1024;
#pragma unroll
  for (int c = t; c < 1024; c += 256)
    prow[c] = sacc[0][c] + sacc[1][c] + sacc[2][c] + sacc[3][c];
}

__global__ void __launch_bounds__(256) kv_reduce(const float* __restrict__ partial,
                                                 float* __restrict__ gf) {
  const int i = blockIdx.x * 256 + threadIdx.x;  // 0..8191
  const int b = i >> 10, e = i & 1023;
  float s = 0.f;
  for (int g = 0; g < 128; ++g)
    s += partial[((int64_t)(b * 128 + g) << 10) + e];
  gf[i] = s;
}

// -------------------------------- out = (Q/||Q||) * gf[b]   (in place) ----
__global__ void __launch_bounds__(256) finalize_out(float* __restrict__ out,
                                                    const float* __restrict__ gf) {
  const int64_t row = (int64_t)blockIdx.x * 4 + (threadIdx.x >> 6);
  const int lane = threadIdx.x & 63;
  const int b = (int)(row >> 12);
  float* rp = out + row * D_DIM;
  const float* gp = gf + (int64_t)b * D_DIM;
  float4 q[4];
#pragma unroll
  for (int p = 0; p < 4; ++p) q[p] = *(const float4*)(rp + (p * 64 + lane) * 4);
  float ss = 0.f;
#pragma unroll
  for (int p = 0; p < 4; ++p)
    ss += q[p].x * q[p].x + q[p].y * q[p].y + q[p].z * q[p].z + q[p].w * q[p].w;
#pragma unroll
  for (int o = 32; o > 0; o >>= 1) ss += __shfl_xor(ss, o);
  const float rn = 1.0f / fmaxf(sqrtf(ss), 1e-12f);
#pragma unroll
  for (int p = 0; p < 4; ++p) {
    const float4 g4 = *(const float4*)(gp + (p * 64 + lane) * 4);
    q[p].x *= rn * g4.x; q[p].y *= rn * g4.y;
    q[p].z *= rn * g4.z; q[p].w *= rn * g4.w;
    *(float4*)(rp + (p * 64 + lane) * 4) = q[p];
  }
}

// -------------------------------------------------------------- launch ----
extern "C" void kernel_launch(void* const* d_in, const int* in_sizes, int n_in,
                              void* d_out, int out_size, void* d_ws, size_t ws_size,
                              hipStream_t stream) {
  const float* x  = (const float*)d_in[0];
  const float* Wq = (const float*)d_in[1];
  const float* Wk = (const float*)d_in[2];
  const float* Wv = (const float*)d_in[3];
  float* out = (float*)d_out;

  uint8_t* w = (uint8_t*)d_ws;
  uint16_t* xb   = (uint16_t*)(w);
  uint16_t* wcat = (uint16_t*)(w + (size_t)67108864);
  uint16_t* Kb   = (uint16_t*)(w + (size_t)73400320);
  uint16_t* Vb   = (uint16_t*)(w + (size_t)140509184);
  float* partial = (float*)(w);                         // aliases xb (dead)
  float* gf      = (float*)(w + (size_t)4194304);

  cast_x_k   <<<32768, 256, 0, stream>>>(x, xb);
  cast_w_k   <<<3072, 256, 0, stream>>>(Wq, Wk, Wv, wcat);
  gemm_qkv8  <<<1536, 512, 0, stream>>>(xb, wcat, out, Kb, Vb);
  kv_partial <<<1024, 256, 0, stream>>>(Kb, Vb, partial);
  kv_reduce  <<<32, 256, 0, stream>>>(partial, gf);
  finalize_out<<<8192, 256, 0, stream>>>(out, gf);
}